// Round 7
// baseline (64.280 us; speedup 1.0000x reference)
//
#include <hip/hip_runtime.h>
#include <math.h>

#define G      26
#define NA     5
#define NC     20
#define NB     128
#define NT     1024
#define GG     (G*G)            // 676
#define CELLS  (NB*NA*GG)       // 432640
#define CH     (NC+5)           // 25
#define CPB    256              // cells per block
#define NBLK   (CELLS/CPB)      // 1690 (exact)
#define IGNORE_THRESH 0.6f
#define OBJ_SCALE   5.0f
#define NOOBJ_SCALE 1.0f
#define CLS_SCALE   1.0f
#define COORD_SCALE 1.0f
#define STRIDE_F    32.0f

typedef float f32x4 __attribute__((ext_vector_type(4)));   // native vec: ok for nontemporal builtins

__device__ __constant__ float c_aw[NA] = {1.08f, 3.42f, 6.63f, 9.42f, 16.62f};
__device__ __constant__ float c_ah[NA] = {1.19f, 4.41f, 11.38f, 5.11f, 10.52f};

__device__ __forceinline__ float sigmoidf(float v) {
    return 1.0f / (1.0f + expf(-v));
}

// -------- Pass 1: parallel target resolution (1 wave per target) --------
__launch_bounds__(256)
__global__ void k_resolve(const float* __restrict__ tg,
                          float* __restrict__ acc,
                          int2* __restrict__ obj_list,
                          int* __restrict__ supp_list) {
    __shared__ int packed[NT];
    int tid = threadIdx.x;
    if (blockIdx.x == 0 && tid < 16) acc[tid] = 0.0f;

    #pragma unroll
    for (int q = 0; q < 4; ++q) {
        int t = tid + q * 256;
        int   b  = (int)tg[t * 6 + 0];
        float cx = tg[t * 6 + 2] * (float)G;
        float cy = tg[t * 6 + 3] * (float)G;
        float gw = tg[t * 6 + 4] * (float)G;
        float gh = tg[t * 6 + 5] * (float)G;
        int gi = (int)floorf(cx);
        int gj = (int)floorf(cy);
        float best = -1.0f;
        int bn = 0, bits = 0;
        #pragma unroll
        for (int a = 0; a < NA; ++a) {
            float inter = fminf(c_aw[a], gw) * fminf(c_ah[a], gh);
            float uni   = c_aw[a] * c_ah[a] + 1e-16f + gw * gh - inter;
            float iou   = inter / uni;
            if (iou > best) { best = iou; bn = a; }      // first max wins (jnp.argmax)
            if (iou > IGNORE_THRESH) bits |= (1 << a);
        }
        int key = (b * G + gj) * G + gi;                 // < 86528, fits 17 bits
        packed[t] = (key << 8) | (bn << 5) | bits;
    }
    __syncthreads();

    int t    = blockIdx.x * 4 + (tid >> 6);              // wave -> target
    int lane = tid & 63;
    int me     = packed[t];
    int mykey  = me >> 8;
    int mybn   = (me >> 5) & 7;
    int mybits = me & 31;

    // agg: bits0-4 used anchors, bits5-9 earlier supp bits, bit10 not-winner
    int agg = 0;
    #pragma unroll
    for (int s = 0; s < 16; ++s) {
        int o  = lane + s * 64;
        int pv = packed[o];
        if ((pv >> 8) == mykey) {
            int obn = (pv >> 5) & 7;
            agg |= (1 << obn);                           // used
            if (o > t && obn == mybn) agg |= (1 << 10);  // later target owns cell
            if (o < t) agg |= (pv & 31) << 5;            // earlier supp rep
        }
    }
    #pragma unroll
    for (int off = 32; off > 0; off >>= 1) agg |= __shfl_xor(agg, off);

    if (lane == 0) {
        int used    = agg & 31;
        int earlier = (agg >> 5) & 31;
        bool winner = !(agg & (1 << 10));
        int cell0 = (mykey / GG) * (NA * GG) + (mykey % GG);
        obj_list[t] = winner ? make_int2(cell0 + mybn * GG, t) : make_int2(-1, -1);
        #pragma unroll
        for (int a = 0; a < NA; ++a) {
            bool s = (mybits >> a & 1) && !(earlier >> a & 1) && !(used >> a & 1);
            supp_list[t * NA + a] = s ? (cell0 + a * GG) : -1;
        }
    }
}

// -------- Pass 2: streaming elementwise + inline loss --------
// 1 cell/thread, 26.8 KB LDS -> 6 blocks/CU (24 waves/CU) for latency hiding.
__launch_bounds__(256, 6)
__global__ void k_main(const float* __restrict__ x,
                       const float* __restrict__ tg,
                       const int2* __restrict__ obj_list,
                       const int* __restrict__ supp_list,
                       float* __restrict__ out,
                       float* __restrict__ acc) {
    __shared__ float stage[CPB * CH];   // 25600 B
    __shared__ int   lmap[CPB];         // -1 plain / -2 supp / >=0 obj target
    __shared__ float red[4][9];

    int tid  = threadIdx.x;
    int base = blockIdx.x * CPB;

    lmap[tid] = -1;

    // issue the 25 independent HBM loads FIRST (in flight during lmap build)
    int cell = base + tid;
    int sp = cell % GG;
    int pa = cell / GG;                                  // b*NA + a
    int a  = pa % NA;
    int i  = sp % G, j = sp / G;
    float aw = c_aw[a], ah = c_ah[a];

    const float* xp = x + (size_t)pa * (CH * GG) + sp;
    float v[CH];
    #pragma unroll
    for (int c = 0; c < CH; ++c) v[c] = xp[(size_t)c * GG];

    __syncthreads();                                     // lmap init done
    #pragma unroll
    for (int k = 0; k < 4; ++k) {                        // 1024 obj slots (L2-hot)
        int2 e = obj_list[tid + k * 256];
        unsigned d = (unsigned)(e.x - base);
        if (d < (unsigned)CPB) lmap[d] = e.y;            // e.x==-1 wraps huge
    }
    #pragma unroll
    for (int k = 0; k < 20; ++k) {                       // 5120 supp slots
        int c = supp_list[tid + k * 256];
        unsigned d = (unsigned)(c - base);
        if (d < (unsigned)CPB) lmap[d] = -2;             // disjoint from obj cells
    }

    float px = sigmoidf(v[0]);
    float py = sigmoidf(v[1]);
    float pconf = sigmoidf(v[4]);
    float bx = px + (float)i;
    float by = py + (float)j;
    float bw = expf(v[2]) * aw;
    float bh = expf(v[3]) * ah;

    float* s = &stage[tid * CH];                         // stride 25 (odd): 2-way, free
    s[0] = bx * STRIDE_F;
    s[1] = by * STRIDE_F;
    s[2] = bw * STRIDE_F;
    s[3] = bh * STRIDE_F;
    s[4] = pconf;
    #pragma unroll
    for (int c = 0; c < NC; ++c) s[5 + c] = sigmoidf(v[5 + c]);

    __syncthreads();                                     // lmap + stage complete

    // coalesced non-temporal float4 copy-out (write-once: don't evict x)
    f32x4* ob = (f32x4*)(out + (size_t)blockIdx.x * (CPB * CH));
    const f32x4* st = (const f32x4*)stage;
    #pragma unroll
    for (int k = 0; k < 6; ++k)
        __builtin_nontemporal_store(st[k * 256 + tid], &ob[k * 256 + tid]);
    if (tid < 64)
        __builtin_nontemporal_store(st[1536 + tid], &ob[1536 + tid]);

    // per-cell loss: {sx, sy, sw, sh, conf_obj, conf_noobj, cls, n_obj, n_noobj}
    float p[9];
    #pragma unroll
    for (int q = 0; q < 9; ++q) p[q] = 0.0f;

    int m = lmap[tid];
    if (m == -1) {                                       // plain noobj cell
        p[5] = pconf * pconf;                            // tconf == 0 here
        p[8] = 1.0f;
    } else if (m >= 0) {                                 // obj cell, target m
        float cx = tg[m * 6 + 2] * (float)G;
        float cy = tg[m * 6 + 3] * (float)G;
        float gw = tg[m * 6 + 4] * (float)G;
        float gh = tg[m * 6 + 5] * (float)G;
        int label = (int)tg[m * 6 + 1];
        float tx = cx - floorf(cx);
        float ty = cy - floorf(cy);
        float tw = logf(gw / aw + 1e-16f);
        float th = logf(gh / ah + 1e-16f);

        float b1x1 = bx - bw * 0.5f, b1x2 = bx + bw * 0.5f;
        float b1y1 = by - bh * 0.5f, b1y2 = by + bh * 0.5f;
        float b2x1 = cx - gw * 0.5f, b2x2 = cx + gw * 0.5f;
        float b2y1 = cy - gh * 0.5f, b2y2 = cy + gh * 0.5f;
        float iw = fmaxf(fminf(b1x2, b2x2) - fmaxf(b1x1, b2x1) + 1.0f, 0.0f);
        float ih = fmaxf(fminf(b1y2, b2y2) - fmaxf(b1y1, b2y1) + 1.0f, 0.0f);
        float inter = iw * ih;
        float a1 = (b1x2 - b1x1 + 1.0f) * (b1y2 - b1y1 + 1.0f);
        float a2 = (b2x2 - b2x1 + 1.0f) * (b2y2 - b2y1 + 1.0f);
        float iou = inter / (a1 + a2 - inter + 1e-16f);

        p[0] = (px - tx) * (px - tx);
        p[1] = (py - ty) * (py - ty);
        p[2] = (v[2] - tw) * (v[2] - tw);
        p[3] = (v[3] - th) * (v[3] - th);
        p[4] = (pconf - iou) * (pconf - iou);
        float cls = 0.0f;
        const float* sc = s + 5;                         // own stage region (sigmoids)
        #pragma unroll
        for (int c = 0; c < NC; ++c) {
            float pcv = fminf(fmaxf(sc[c], 1e-12f), 1.0f - 1e-12f);
            float tc = (c == label) ? 1.0f : 0.0f;
            cls -= tc * logf(pcv) + (1.0f - tc) * logf(1.0f - pcv);
        }
        p[6] = cls;
        p[7] = 1.0f;
    }                                                    // m == -2: suppressed, skip

    #pragma unroll
    for (int o = 32; o > 0; o >>= 1) {
        #pragma unroll
        for (int q = 0; q < 9; ++q) p[q] += __shfl_down(p[q], o);
    }
    int lane = tid & 63, wid = tid >> 6;
    if (lane == 0) {
        #pragma unroll
        for (int q = 0; q < 9; ++q) red[wid][q] = p[q];
    }
    __syncthreads();
    if (tid < 9) {
        float sum = red[0][tid] + red[1][tid] + red[2][tid] + red[3][tid];
        if (sum != 0.0f) atomicAdd(&acc[tid], sum);
    }
}

// -------- Pass 3: finalize scalar loss (kernel boundary = coherence) --------
__global__ void k_final(const float* __restrict__ acc, float* __restrict__ loss_out) {
    float n_obj   = acc[7];
    float n_noobj = acc[8];
    float l = COORD_SCALE * (acc[0] + acc[1] + acc[2] + acc[3]) / n_obj
            + OBJ_SCALE * acc[4] / n_obj
            + NOOBJ_SCALE * acc[5] / n_noobj
            + CLS_SCALE * acc[6] / (n_obj * (float)NC);
    *loss_out = l;
}

extern "C" void kernel_launch(void* const* d_in, const int* in_sizes, int n_in,
                              void* d_out, int out_size, void* d_ws, size_t ws_size,
                              hipStream_t stream) {
    const float* x  = (const float*)d_in[0];
    const float* tg = (const float*)d_in[1];
    float* out = (float*)d_out;

    char* ws = (char*)d_ws;
    float* acc       = (float*)ws;                   // 16 floats
    int2*  obj_list  = (int2*)(ws + 64);             // 1024 * int2 (all slots written)
    int*   supp_list = (int*)(ws + 64 + NT * 8);     // 5120 ints  (all slots written)

    k_resolve<<<NT / 4, 256, 0, stream>>>(tg, acc, obj_list, supp_list);
    k_main<<<NBLK, 256, 0, stream>>>(x, tg, obj_list, supp_list, out, acc);
    k_final<<<1, 1, 0, stream>>>(acc, out + (size_t)CELLS * CH);
}